// Round 19
// baseline (300.129 us; speedup 1.0000x reference)
//
#include <hip/hip_runtime.h>
#include <math.h>

#define NN 100000
#define EE 1600000
#define HH 128
#define DX 64
#define CC 8
#define EPSV 1e-5f

#define NB 782          // ceil(NN/128) coarse buckets of 128 nodes
#define BCAP 4096       // fixed tmp capacity per bucket (line-aligned)
#define EPB 8192        // edges per k_bin block
#define NBLK_BIN ((EE + EPB - 1) / EPB)    // 196

typedef unsigned int u32;
typedef unsigned short u16;
typedef unsigned char u8;
typedef __attribute__((ext_vector_type(8))) short short8v;
typedef __attribute__((ext_vector_type(4))) float float4v;
typedef __attribute__((ext_vector_type(2))) float float2v;

__device__ __forceinline__ float bf2f(u16 h) {
    u32 u = ((u32)h) << 16;
    union { u32 u; float f; } c; c.u = u; return c.f;
}
__device__ __forceinline__ u16 f2b(float f) {
    union { float f; u32 u; } c; c.f = f;
    u32 r = (c.u + 0x7fffu + ((c.u >> 16) & 1u)) >> 16;
    return (u16)r;
}

// ---------------- setup: zero stats/btot, cursors, weights, cast x->bf16 ----------------

__global__ void k_setup(const float* __restrict__ sctx,
                        const float* __restrict__ W1, const float* __restrict__ W2,
                        const float* __restrict__ x,
                        float* __restrict__ stats, int* __restrict__ btot,
                        int* __restrict__ gcursor,
                        float* __restrict__ cvec,
                        u16* __restrict__ Bt1, u16* __restrict__ Bt2,
                        u16* __restrict__ xb) {
    int i = blockIdx.x * 256 + threadIdx.x;
    if (i < 512) stats[i] = 0.f;
    if (i < NB) { btot[i] = 0; gcursor[i] = i * BCAP; }
    if (i < 128 * 64) {
        int col = i >> 6, k = i & 63;
        Bt1[i] = f2b(W1[(size_t)k * HH + col]);
    } else if (i < 128 * 64 + 128 * 128) {
        int j = i - 128 * 64;
        int col = j >> 7, k = j & 127;
        Bt2[j] = f2b(W2[(size_t)k * HH + col]);
    }
    if (blockIdx.x == 96 && threadIdx.x < 128) {
        int f = threadIdx.x;
        float s = 0.f;
        #pragma unroll
        for (int j = 0; j < 64; ++j) s += sctx[j] * W1[(64 + j) * HH + f];
        cvec[f] = s;
    }
    if (i < NN * (DX / 4)) {            // cast 4 fp32 -> 4 bf16 per thread
        float4 v = ((const float4*)x)[i];
        uint2 pk;
        pk.x = (u32)f2b(v.x) | ((u32)f2b(v.y) << 16);
        pk.y = (u32)f2b(v.z) | ((u32)f2b(v.w) << 16);
        ((uint2*)xb)[i] = pk;
    }
}

// bin edges: LDS-group by bucket, flush line-aligned padded runs; no per-edge atomics
__global__ __launch_bounds__(1024) void k_bin(const int* __restrict__ src,
                                              const int* __restrict__ dst,
                                              int* __restrict__ btot,
                                              int* __restrict__ gcursor,
                                              u32* __restrict__ tmp) {
    __shared__ u32 rec[EPB];              // 32 KB
    __shared__ int bcnt[NB], lstart[NB], gbase[NB], bofs[NB];
    __shared__ int part[1024];
    int t = threadIdx.x;
    int e0 = blockIdx.x * EPB;
    if (t < NB) { bcnt[t] = 0; bofs[t] = 0; }
    __syncthreads();
    int myd[8], mys[8];
    #pragma unroll
    for (int i = 0; i < 8; ++i) {
        int e = e0 + t + i * 1024;
        int d = -1, s = 0;
        if (e < EE) {
            d = dst[e]; s = src[e];
            atomicAdd(&bcnt[d >> 7], 1);
        }
        myd[i] = d; mys[i] = s;
    }
    __syncthreads();
    int c = (t < NB) ? bcnt[t] : 0;
    part[t] = c; __syncthreads();
    for (int d = 1; d < 1024; d <<= 1) {
        int xk = (t >= d) ? part[t - d] : 0;
        __syncthreads();
        part[t] += xk;
        __syncthreads();
    }
    if (t < NB) {
        lstart[t] = part[t] - c;
        if (c) {
            gbase[t] = atomicAdd(&gcursor[t], (c + 15) & ~15);
            atomicAdd(&btot[t], c);
        }
    }
    __syncthreads();
    #pragma unroll
    for (int i = 0; i < 8; ++i) {
        int d = myd[i];
        if (d >= 0) {
            int b = d >> 7;
            int lp = atomicAdd(&bofs[b], 1);
            rec[lstart[b] + lp] = (u32)mys[i] | ((u32)(d & 127) << 17);
        }
    }
    __syncthreads();
    int wv = t >> 6, ln = t & 63;
    for (int b = wv; b < NB; b += 16) {
        int n = bcnt[b];
        if (n) {
            int np = (n + 15) & ~15;
            int gb = gbase[b], ls = lstart[b];
            for (int j = ln; j < np; j += 64)
                tmp[gb + j] = (j < n) ? rec[ls + j] : 0xFFFFFFFFu;
        }
    }
}

__global__ void k_bscan(const int* __restrict__ btot, int* __restrict__ bbase) {
    __shared__ int ls[1024];
    int t = threadIdx.x;
    int v = (t < NB) ? btot[t] : 0;
    ls[t] = v; __syncthreads();
    for (int d = 1; d < 1024; d <<= 1) {
        int x = (t >= d) ? ls[t - d] : 0;
        __syncthreads();
        ls[t] += x;
        __syncthreads();
    }
    if (t < NB) bbase[t] = ls[t] - v;   // exclusive
}

__global__ __launch_bounds__(256) void k_csrA(const u32* __restrict__ tmp,
                                              const int* __restrict__ gcursor,
                                              const int* __restrict__ bbase,
                                              int* __restrict__ rowp,
                                              int* __restrict__ cnt,
                                              float* __restrict__ dinv) {
    __shared__ int lcnt[128];
    __shared__ int lofs[128];
    int b = blockIdx.x, t = threadIdx.x;
    if (t < 128) lcnt[t] = 0;
    __syncthreads();
    int beg = b * BCAP, end = gcursor[b];
    for (int i = beg + t; i < end; i += 256) {
        u32 r = tmp[i];
        if (r != 0xFFFFFFFFu) atomicAdd(&lcnt[(r >> 17) & 127], 1);
    }
    __syncthreads();
    int c = (t < 128) ? lcnt[t] : 0;
    if (t < 128) lofs[t] = c;
    __syncthreads();
    for (int d = 1; d < 128; d <<= 1) {
        int x = 0;
        if (t < 128 && t >= d) x = lofs[t - d];
        __syncthreads();
        if (t < 128) lofs[t] += x;
        __syncthreads();
    }
    if (t < 128) {
        int n = (b << 7) + t;
        if (n < NN) {
            rowp[n] = bbase[b] + lofs[t] - c;
            cnt[n] = c;
            dinv[n] = rsqrtf(1.0f + (float)c);
        }
    }
}

// place records at CSR positions + weights; accumulate rowsum = sum(w) + dinv^2
__global__ __launch_bounds__(256) void k_csrB(const u32* __restrict__ tmp,
                                              const int* __restrict__ gcursor,
                                              const int* __restrict__ rowp,
                                              const float* __restrict__ dinv,
                                              int2* __restrict__ ew,
                                              float* __restrict__ rowsum) {
    __shared__ int lcur[128];
    __shared__ float ldin[128];
    __shared__ float lsum[128];
    int b = blockIdx.x, t = threadIdx.x;
    int n0 = b << 7;
    if (t < 128) {
        int n = n0 + t;
        lcur[t] = (n < NN) ? rowp[n] : 0;
        float dv = (n < NN) ? dinv[n] : 0.f;
        ldin[t] = dv;
        lsum[t] = dv * dv;
    }
    __syncthreads();
    int beg = b * BCAP;
    int end = gcursor[b];
    for (int i = beg + t; i < end; i += 256) {
        u32 r = tmp[i];
        if (r == 0xFFFFFFFFu) continue;   // padding sentinel
        int s = r & 0x1FFFF;
        int dl = (r >> 17) & 127;
        int pos = atomicAdd(&lcur[dl], 1);
        float w = dinv[s] * ldin[dl];
        ew[pos] = make_int2(s, __float_as_int(w));
        atomicAdd(&lsum[dl], w);
    }
    __syncthreads();
    if (t < 128) {
        int n = n0 + t;
        if (n < NN) rowsum[n] = lsum[t];
    }
}

// ---------------- SpMM layer 1: xp(bf16,64d) = A @ xb ----------------

__global__ __launch_bounds__(256) void k_spmm1(const u16* __restrict__ xb,
                                               const int* __restrict__ rowp,
                                               const int* __restrict__ cnt,
                                               const int2* __restrict__ ew,
                                               const float* __restrict__ dinv,
                                               u16* __restrict__ xp) {
    int wave = threadIdx.x >> 6;
    int lane = threadIdx.x & 63;
    int n = blockIdx.x * 4 + wave;          // grid exact: 25000 blocks
    int o = lane >> 3, li = lane & 7;       // o: edge slot 0..7, li: 16B chunk
    int f0 = li * 8;                        // 8 bf16 elements
    float dn = dinv[n];
    float a[8];
    {
        uint4 r = *(const uint4*)&xb[(size_t)n * DX + f0];
        float sc = (o == 0) ? dn * dn : 0.f;
        u32 wd[4] = {r.x, r.y, r.z, r.w};
        #pragma unroll
        for (int k = 0; k < 4; ++k) {
            a[k * 2 + 0] = sc * bf2f((u16)(wd[k] & 0xffff));
            a[k * 2 + 1] = sc * bf2f((u16)(wd[k] >> 16));
        }
    }
    int start = rowp[n], len = cnt[n];
    #pragma unroll 4
    for (int j = o; j < len; j += 8) {
        int2 e = ew[start + j];
        float wv = __int_as_float(e.y);
        uint4 r = *(const uint4*)&xb[(size_t)e.x * DX + f0];
        u32 wd[4] = {r.x, r.y, r.z, r.w};
        #pragma unroll
        for (int k = 0; k < 4; ++k) {
            a[k * 2 + 0] = fmaf(bf2f((u16)(wd[k] & 0xffff)), wv, a[k * 2 + 0]);
            a[k * 2 + 1] = fmaf(bf2f((u16)(wd[k] >> 16)),    wv, a[k * 2 + 1]);
        }
    }
    #pragma unroll
    for (int k = 0; k < 8; ++k) {
        a[k] += __shfl_xor(a[k], 8);
        a[k] += __shfl_xor(a[k], 16);
        a[k] += __shfl_xor(a[k], 32);
    }
    if (o == 0) {
        uint4 pk;
        u32 w0 = (u32)f2b(a[0]) | ((u32)f2b(a[1]) << 16);
        u32 w1 = (u32)f2b(a[2]) | ((u32)f2b(a[3]) << 16);
        u32 w2 = (u32)f2b(a[4]) | ((u32)f2b(a[5]) << 16);
        u32 w3 = (u32)f2b(a[6]) | ((u32)f2b(a[7]) << 16);
        pk = make_uint4(w0, w1, w2, w3);
        *(uint4*)&xp[(size_t)n * DX + f0] = pk;
    }
}

// ---------------- MFMA GEMM1: hbuf = relu(xp @ W1x + rowsum*cvec + b1) ----------------

__global__ __launch_bounds__(256) void k_mgemm1(const u16* __restrict__ xp,
                                                const u16* __restrict__ Bt1,
                                                const float* __restrict__ cvec,
                                                const float* __restrict__ b1,
                                                const float* __restrict__ rowsum,
                                                u16* __restrict__ outp) {
    __shared__ u16 As[64 * 64];
    __shared__ u16 Bs[128 * 64];    // reused as Cs (64 x 128)
    __shared__ float cvs[128], bs[128], rsum[64];
    int t = threadIdx.x;
    int n0 = blockIdx.x * 64;
    if (t < 128) { cvs[t] = cvec[t]; bs[t] = b1[t]; }
    if (t < 64) {
        int n = n0 + t;
        rsum[t] = (n < NN) ? rowsum[n] : 0.f;
    }

    #pragma unroll
    for (int l = 0; l < 4; ++l) {
        int idx = t + l * 256;
        int col = idx >> 3, kg = idx & 7;
        uint4 v = *(const uint4*)&Bt1[idx * 8];
        u32 byte = (u32)(col * 128 + kg * 16) ^ ((col & 7) << 4);
        *(uint4*)((char*)Bs + byte) = v;
    }
    #pragma unroll
    for (int l = 0; l < 2; ++l) {
        int idx = t + l * 256;
        int r = idx >> 3, kg = idx & 7;
        int n = n0 + r; if (n > NN - 1) n = NN - 1;
        uint4 v = *(const uint4*)&xp[(size_t)n * DX + kg * 8];
        u32 byte = (u32)(r * 128 + kg * 16) ^ ((r & 7) << 4);
        *(uint4*)((char*)As + byte) = v;
    }
    __syncthreads();

    int w = t >> 6, lane = t & 63;
    int rl = lane & 15, kq = lane >> 4;
    int rbase = w * 16 + rl;
    float4v acc[8];
    #pragma unroll
    for (int nt = 0; nt < 8; ++nt) acc[nt] = (float4v){0.f, 0.f, 0.f, 0.f};

    #pragma unroll
    for (int kk = 0; kk < 2; ++kk) {
        u32 ab = (u32)(rbase * 128 + kk * 64 + kq * 16) ^ ((rbase & 7) << 4);
        short8v af = *(const short8v*)((const char*)As + ab);
        #pragma unroll
        for (int nt = 0; nt < 8; ++nt) {
            int col = nt * 16 + rl;
            u32 bb = (u32)(col * 128 + kk * 64 + kq * 16) ^ ((col & 7) << 4);
            short8v bf = *(const short8v*)((const char*)Bs + bb);
            acc[nt] = __builtin_amdgcn_mfma_f32_16x16x32_bf16(af, bf, acc[nt], 0, 0, 0);
        }
    }
    __syncthreads();
    #pragma unroll
    for (int nt = 0; nt < 8; ++nt) {
        int col = nt * 16 + rl;
        #pragma unroll
        for (int j = 0; j < 4; ++j) {
            int row = w * 16 + kq * 4 + j;
            float o = acc[nt][j] + rsum[row] * cvs[col] + bs[col];
            u16 v = f2b(fmaxf(o, 0.f));
            u32 byte = (u32)(row * 256 + col * 2) ^ ((row & 7) << 4);
            *(u16*)((char*)Bs + byte) = v;
        }
    }
    __syncthreads();
    #pragma unroll
    for (int l = 0; l < 4; ++l) {
        int idx = t + l * 256;
        int r = idx >> 4, kg = idx & 15;
        u32 byte = (u32)(r * 256 + kg * 16) ^ ((r & 7) << 4);
        uint4 v = *(const uint4*)((const char*)Bs + byte);
        int n = n0 + r;
        if (n < NN) *(uint4*)&outp[(size_t)n * HH + kg * 8] = v;
    }
}

// ---------------- MFMA GEMM2: h8(fp8) = bn1(hbuf) @ W2 ----------------

__global__ __launch_bounds__(256) void k_mgemm2(const u16* __restrict__ hin,
                                                const u16* __restrict__ Bt2,
                                                const float* __restrict__ stats,
                                                const float* __restrict__ g,
                                                const float* __restrict__ be,
                                                u8* __restrict__ outp8) {
    __shared__ u16 As[64 * 128];    // staging; reused as fp8 Cs (64 x 128 B)
    __shared__ u16 Bs[128 * 128];
    __shared__ float asc[128], csc[128];
    int t = threadIdx.x;
    int n0 = blockIdx.x * 64;
    if (t < 128) {
        float mu  = stats[t] * (1.0f / NN);
        float var = stats[128 + t] * (1.0f / NN) - mu * mu;
        float rs  = rsqrtf(var + EPSV);
        float a   = g[t] * rs;
        asc[t] = a;
        csc[t] = be[t] - mu * a;
    }
    #pragma unroll
    for (int l = 0; l < 8; ++l) {
        int idx = t + l * 256;
        int col = idx >> 4, kg = idx & 15;
        uint4 v = *(const uint4*)&Bt2[idx * 8];
        u32 byte = (u32)(col * 256 + kg * 16) ^ ((col & 7) << 4);
        *(uint4*)((char*)Bs + byte) = v;
    }
    __syncthreads();
    #pragma unroll
    for (int l = 0; l < 4; ++l) {
        int idx = t + l * 256;
        int r = idx >> 4, kg = idx & 15;
        int n = n0 + r; if (n > NN - 1) n = NN - 1;
        uint4 v = *(const uint4*)&hin[(size_t)n * HH + kg * 8];
        u32 wds[4] = {v.x, v.y, v.z, v.w};
        u32 pk[2][2];
        #pragma unroll
        for (int q = 0; q < 4; ++q) {
            int k = kg * 8 + q * 2;
            float x0 = bf2f((u16)(wds[q] & 0xffff));
            float x1 = bf2f((u16)(wds[q] >> 16));
            u16 o0 = f2b(fmaxf(fmaf(x0, asc[k],     csc[k]),     0.f));
            u16 o1 = f2b(fmaxf(fmaf(x1, asc[k + 1], csc[k + 1]), 0.f));
            pk[q >> 1][q & 1] = (u32)o0 | ((u32)o1 << 16);
        }
        uint4 ov = make_uint4(pk[0][0], pk[0][1], pk[1][0], pk[1][1]);
        u32 byte = (u32)(r * 256 + kg * 16) ^ ((r & 7) << 4);
        *(uint4*)((char*)As + byte) = ov;
    }
    __syncthreads();

    int w = t >> 6, lane = t & 63;
    int rl = lane & 15, kq = lane >> 4;
    int rbase = w * 16 + rl;
    float4v acc[8];
    #pragma unroll
    for (int nt = 0; nt < 8; ++nt) acc[nt] = (float4v){0.f, 0.f, 0.f, 0.f};

    #pragma unroll
    for (int kk = 0; kk < 4; ++kk) {
        u32 ab = (u32)(rbase * 256 + kk * 64 + kq * 16) ^ ((rbase & 7) << 4);
        short8v af = *(const short8v*)((const char*)As + ab);
        #pragma unroll
        for (int nt = 0; nt < 8; ++nt) {
            int col = nt * 16 + rl;
            u32 bb = (u32)(col * 256 + kk * 64 + kq * 16) ^ ((col & 7) << 4);
            short8v bf = *(const short8v*)((const char*)Bs + bb);
            acc[nt] = __builtin_amdgcn_mfma_f32_16x16x32_bf16(af, bf, acc[nt], 0, 0, 0);
        }
    }
    __syncthreads();
    // epilogue: acc -> fp8 Cs (64 rows x 128 B, chunk-swizzled)
    u8* Cs8 = (u8*)As;
    #pragma unroll
    for (int nt = 0; nt < 8; ++nt) {
        int col = nt * 16 + rl;
        #pragma unroll
        for (int j = 0; j < 4; ++j) {
            int row = w * 16 + kq * 4 + j;
            u32 pk8 = __builtin_amdgcn_cvt_pk_fp8_f32(acc[nt][j], acc[nt][j], 0, false);
            u32 byte = (u32)(row * 128 + col) ^ ((row & 7) << 4);
            Cs8[byte] = (u8)(pk8 & 0xff);
        }
    }
    __syncthreads();
    #pragma unroll
    for (int l = 0; l < 2; ++l) {
        int idx = t + l * 256;
        int r = idx >> 3, kg = idx & 7;
        u32 byte = (u32)(r * 128 + kg * 16) ^ ((r & 7) << 4);
        uint4 v = *(const uint4*)(Cs8 + byte);
        int n = n0 + r;
        if (n < NN) *(uint4*)&outp8[(size_t)n * HH + kg * 16] = v;
    }
}

// ---------------- SpMM layer 2 (fp8 gather): hout = relu(A @ h8 + b2) ----------------
// QUARTER-wave (16 lanes x 8B = full 128B fp8 row) per edge; 4 edge slots,
// unroll 8 -> 32 gathers in flight; 8 regs, 2-hop reduce.

__global__ __launch_bounds__(256) void k_spmm2(const u8* __restrict__ h8,
                                               const int* __restrict__ rowp,
                                               const int* __restrict__ cnt,
                                               const int2* __restrict__ ew,
                                               const float* __restrict__ dinv,
                                               const float* __restrict__ b,
                                               u16* __restrict__ hout) {
    int wave = threadIdx.x >> 6;
    int lane = threadIdx.x & 63;
    int n = blockIdx.x * 4 + wave;          // grid exact: 25000 blocks
    int q = lane >> 4, li = lane & 15;      // q: edge slot 0..3, li: 8B chunk
    int f0 = li * 8;                        // 8 fp8 features per lane
    float dn = dinv[n];
    float a[8];
    {
        uint2 r = *(const uint2*)&h8[(size_t)n * HH + f0];
        float sc = (q == 0) ? dn * dn : 0.f;
        u32 wd[2] = {r.x, r.y};
        #pragma unroll
        for (int k = 0; k < 2; ++k) {
            float2v lo = __builtin_amdgcn_cvt_pk_f32_fp8(wd[k], false);
            float2v hi = __builtin_amdgcn_cvt_pk_f32_fp8(wd[k], true);
            a[k * 4 + 0] = sc * lo[0];
            a[k * 4 + 1] = sc * lo[1];
            a[k * 4 + 2] = sc * hi[0];
            a[k * 4 + 3] = sc * hi[1];
        }
    }
    int start = rowp[n], len = cnt[n];
    #pragma unroll 8
    for (int j = q; j < len; j += 4) {
        int2 e = ew[start + j];
        float wv = __int_as_float(e.y);
        uint2 r = *(const uint2*)&h8[(size_t)e.x * HH + f0];
        u32 wd[2] = {r.x, r.y};
        #pragma unroll
        for (int k = 0; k < 2; ++k) {
            float2v lo = __builtin_amdgcn_cvt_pk_f32_fp8(wd[k], false);
            float2v hi = __builtin_amdgcn_cvt_pk_f32_fp8(wd[k], true);
            a[k * 4 + 0] = fmaf(lo[0], wv, a[k * 4 + 0]);
            a[k * 4 + 1] = fmaf(lo[1], wv, a[k * 4 + 1]);
            a[k * 4 + 2] = fmaf(hi[0], wv, a[k * 4 + 2]);
            a[k * 4 + 3] = fmaf(hi[1], wv, a[k * 4 + 3]);
        }
    }
    #pragma unroll
    for (int k = 0; k < 8; ++k) {
        a[k] += __shfl_xor(a[k], 16);
        a[k] += __shfl_xor(a[k], 32);
    }
    if (q == 0) {
        float4 b0 = *(const float4*)&b[f0];
        float4 b1 = *(const float4*)&b[f0 + 4];
        float bb[8] = {b0.x, b0.y, b0.z, b0.w, b1.x, b1.y, b1.z, b1.w};
        u32 ow[4];
        #pragma unroll
        for (int k = 0; k < 4; ++k) {
            float v0 = fmaxf(a[k * 2 + 0] + bb[k * 2 + 0], 0.f);
            float v1 = fmaxf(a[k * 2 + 1] + bb[k * 2 + 1], 0.f);
            ow[k] = (u32)f2b(v0) | ((u32)f2b(v1) << 16);
        }
        *(uint4*)&hout[(size_t)n * HH + f0] = make_uint4(ow[0], ow[1], ow[2], ow[3]);
    }
}

// ---------------- BN stats (streaming, separate) ----------------

__global__ __launch_bounds__(256) void k_stats(const u16* __restrict__ h,
                                               float* __restrict__ sums) {
    __shared__ float4 ls[4][64];
    int t = threadIdx.x;
    int lane = t & 63, wave = t >> 6;
    int f0 = lane * 2;
    float s0 = 0.f, s1 = 0.f, q0 = 0.f, q1 = 0.f;
    for (int row = blockIdx.x * 4 + wave; row < NN; row += gridDim.x * 4) {
        u32 v = *(const u32*)&h[(size_t)row * HH + f0];
        float a = bf2f((u16)(v & 0xffff));
        float c = bf2f((u16)(v >> 16));
        s0 += a; q0 += a * a;
        s1 += c; q1 += c * c;
    }
    ls[wave][lane] = make_float4(s0, s1, q0, q1);
    __syncthreads();
    if (wave == 0) {
        float4 r0 = ls[0][lane], r1 = ls[1][lane], r2 = ls[2][lane], r3 = ls[3][lane];
        atomicAdd(&sums[f0 + 0], r0.x + r1.x + r2.x + r3.x);
        atomicAdd(&sums[f0 + 1], r0.y + r1.y + r2.y + r3.y);
        atomicAdd(&sums[128 + f0 + 0], r0.z + r1.z + r2.z + r3.z);
        atomicAdd(&sums[128 + f0 + 1], r0.w + r1.w + r2.w + r3.w);
    }
}

// ---------------- output head ----------------

__global__ __launch_bounds__(256) void k_out(const u16* __restrict__ h,
                                             const float* __restrict__ stats,
                                             const float* __restrict__ g,
                                             const float* __restrict__ be,
                                             const float* __restrict__ Wout,
                                             const float* __restrict__ bout,
                                             float* __restrict__ out) {
    __shared__ float hs[32][132];
    __shared__ float Wl[128][8];
    __shared__ float asc[128], csc[128];
    int t = threadIdx.x;
    if (t < 128) {
        float mu  = stats[256 + t] * (1.0f / NN);
        float var = stats[384 + t] * (1.0f / NN) - mu * mu;
        float rs  = rsqrtf(var + EPSV);
        float a   = g[t] * rs;
        asc[t] = a;
        csc[t] = be[t] - mu * a;
    }
    #pragma unroll
    for (int l = 0; l < 4; ++l) {
        int idx = t + l * 256;
        Wl[idx >> 3][idx & 7] = Wout[idx];
    }
    __syncthreads();

    int n0 = blockIdx.x * 32;
    #pragma unroll
    for (int l = 0; l < 2; ++l) {
        int idx = t + l * 256;
        int r = idx >> 4;
        int kg = idx & 15;
        uint4 v = *(const uint4*)&h[(size_t)(n0 + r) * HH + kg * 8];
        u32 w[4] = {v.x, v.y, v.z, v.w};
        int kk = kg * 8;
        #pragma unroll
        for (int qq = 0; qq < 4; ++qq) {
            float x0 = bf2f((u16)(w[qq] & 0xffff));
            float x1 = bf2f((u16)(w[qq] >> 16));
            hs[r][kk + qq * 2 + 0] = fmaxf(fmaf(x0, asc[kk + qq * 2 + 0], csc[kk + qq * 2 + 0]), 0.f);
            hs[r][kk + qq * 2 + 1] = fmaxf(fmaf(x1, asc[kk + qq * 2 + 1], csc[kk + qq * 2 + 1]), 0.f);
        }
    }
    __syncthreads();

    int c = t & 7, rl = t >> 3;
    float acc = 0.f;
    #pragma unroll 8
    for (int k = 0; k < 128; ++k) acc = fmaf(hs[rl][k], Wl[k][c], acc);
    out[(size_t)(n0 + rl) * CC + c] = acc + bout[c];
}

// ---------------- launch ----------------

extern "C" void kernel_launch(void* const* d_in, const int* in_sizes, int n_in,
                              void* d_out, int out_size, void* d_ws, size_t ws_size,
                              hipStream_t stream) {
    const float* x    = (const float*)d_in[0];
    const int*   src  = (const int*)d_in[1];
    const int*   dst  = (const int*)d_in[2];
    const float* sctx = (const float*)d_in[3];
    const float* W1   = (const float*)d_in[4];
    const float* b1   = (const float*)d_in[5];
    const float* g1   = (const float*)d_in[6];
    const float* be1  = (const float*)d_in[7];
    const float* W2   = (const float*)d_in[8];
    const float* b2   = (const float*)d_in[9];
    const float* g2   = (const float*)d_in[10];
    const float* be2  = (const float*)d_in[11];
    const float* Wout = (const float*)d_in[12];
    const float* bout = (const float*)d_in[13];
    float* out = (float*)d_out;

    char* p = (char*)d_ws;
    auto carve = [&](size_t bytes) -> char* {
        char* r = p;
        p += (bytes + 255) & ~(size_t)255;
        return r;
    };
    u16*   hbuf    = (u16*)carve((size_t)NN * HH * 2);
    u8*    h8      = (u8*)carve((size_t)NN * HH);
    u16*   xb      = (u16*)carve((size_t)NN * DX * 2);
    u16*   xp      = (u16*)carve((size_t)NN * DX * 2);
    int2*  ew      = (int2*)carve((size_t)EE * 8 + 16);
    u32*   tmp     = (u32*)carve((size_t)NB * BCAP * 4 + 16);
    int*   cnt     = (int*)carve((size_t)NN * 4);
    int*   rowp    = (int*)carve((size_t)NN * 4);
    int*   gcursor = (int*)carve((size_t)NB * 4);
    int*   btot    = (int*)carve((size_t)NB * 4);
    int*   bbase   = (int*)carve((size_t)NB * 4);
    float* dinv    = (float*)carve((size_t)NN * 4);
    float* rowsum  = (float*)carve((size_t)NN * 4);
    float* cvec    = (float*)carve(128 * 4);
    float* stats   = (float*)carve(512 * 4);
    u16*   Bt1     = (u16*)carve(128 * 64 * 2);
    u16*   Bt2     = (u16*)carve(128 * 128 * 2);

    k_setup<<<(NN * (DX / 4) + 255) / 256, 256, 0, stream>>>(
        sctx, W1, W2, x, stats, btot, gcursor, cvec, Bt1, Bt2, xb);
    k_bin<<<NBLK_BIN, 1024, 0, stream>>>(src, dst, btot, gcursor, tmp);
    k_bscan<<<1, 1024, 0, stream>>>(btot, bbase);
    k_csrA<<<NB, 256, 0, stream>>>(tmp, gcursor, bbase, rowp, cnt, dinv);
    k_csrB<<<NB, 256, 0, stream>>>(tmp, gcursor, rowp, dinv, ew, rowsum);

    k_spmm1<<<NN / 4, 256, 0, stream>>>(xb, rowp, cnt, ew, dinv, xp);
    k_mgemm1<<<(NN + 63) / 64, 256, 0, stream>>>(xp, Bt1, cvec, b1, rowsum, hbuf);
    k_stats<<<512, 256, 0, stream>>>(hbuf, stats);
    k_mgemm2<<<(NN + 63) / 64, 256, 0, stream>>>(hbuf, Bt2, stats, g1, be1, h8);
    k_spmm2<<<NN / 4, 256, 0, stream>>>(h8, rowp, cnt, ew, dinv, b2, hbuf);
    k_stats<<<512, 256, 0, stream>>>(hbuf, stats + 256);
    k_out<<<NN / 32, 256, 0, stream>>>(hbuf, stats, g2, be2, Wout, bout, out);
}

// Round 20
// 278.489 us; speedup vs baseline: 1.0777x; 1.0777x over previous
//
#include <hip/hip_runtime.h>
#include <math.h>

#define NN 100000
#define EE 1600000
#define HH 128
#define DX 64
#define CC 8
#define EPSV 1e-5f

#define NB 782          // ceil(NN/128) coarse buckets of 128 nodes
#define BCAP 4096       // fixed tmp capacity per bucket (line-aligned)
#define EPB 8192        // edges per k_bin block
#define NBLK_BIN ((EE + EPB - 1) / EPB)    // 196

typedef unsigned int u32;
typedef unsigned short u16;
typedef unsigned char u8;
typedef __attribute__((ext_vector_type(8))) short short8v;
typedef __attribute__((ext_vector_type(4))) float float4v;
typedef __attribute__((ext_vector_type(2))) float float2v;

__device__ __forceinline__ float bf2f(u16 h) {
    u32 u = ((u32)h) << 16;
    union { u32 u; float f; } c; c.u = u; return c.f;
}
__device__ __forceinline__ u16 f2b(float f) {
    union { float f; u32 u; } c; c.f = f;
    u32 r = (c.u + 0x7fffu + ((c.u >> 16) & 1u)) >> 16;
    return (u16)r;
}

// ---------------- setup: zero stats/btot, cursors, weights, cast x->bf16 ----------------

__global__ void k_setup(const float* __restrict__ sctx,
                        const float* __restrict__ W1, const float* __restrict__ W2,
                        const float* __restrict__ x,
                        float* __restrict__ stats, int* __restrict__ btot,
                        int* __restrict__ gcursor,
                        float* __restrict__ cvec,
                        u16* __restrict__ Bt1, u16* __restrict__ Bt2,
                        u16* __restrict__ xb) {
    int i = blockIdx.x * 256 + threadIdx.x;
    if (i < 512) stats[i] = 0.f;
    if (i < NB) { btot[i] = 0; gcursor[i] = i * BCAP; }
    if (i < 128 * 64) {
        int col = i >> 6, k = i & 63;
        Bt1[i] = f2b(W1[(size_t)k * HH + col]);
    } else if (i < 128 * 64 + 128 * 128) {
        int j = i - 128 * 64;
        int col = j >> 7, k = j & 127;
        Bt2[j] = f2b(W2[(size_t)k * HH + col]);
    }
    if (blockIdx.x == 96 && threadIdx.x < 128) {
        int f = threadIdx.x;
        float s = 0.f;
        #pragma unroll
        for (int j = 0; j < 64; ++j) s += sctx[j] * W1[(64 + j) * HH + f];
        cvec[f] = s;
    }
    if (i < NN * (DX / 4)) {            // cast 4 fp32 -> 4 bf16 per thread
        float4 v = ((const float4*)x)[i];
        uint2 pk;
        pk.x = (u32)f2b(v.x) | ((u32)f2b(v.y) << 16);
        pk.y = (u32)f2b(v.z) | ((u32)f2b(v.w) << 16);
        ((uint2*)xb)[i] = pk;
    }
}

// bin edges: LDS-group by bucket, flush line-aligned padded runs; no per-edge atomics
__global__ __launch_bounds__(1024) void k_bin(const int* __restrict__ src,
                                              const int* __restrict__ dst,
                                              int* __restrict__ btot,
                                              int* __restrict__ gcursor,
                                              u32* __restrict__ tmp) {
    __shared__ u32 rec[EPB];              // 32 KB
    __shared__ int bcnt[NB], lstart[NB], gbase[NB], bofs[NB];
    __shared__ int part[1024];
    int t = threadIdx.x;
    int e0 = blockIdx.x * EPB;
    if (t < NB) { bcnt[t] = 0; bofs[t] = 0; }
    __syncthreads();
    int myd[8], mys[8];
    #pragma unroll
    for (int i = 0; i < 8; ++i) {
        int e = e0 + t + i * 1024;
        int d = -1, s = 0;
        if (e < EE) {
            d = dst[e]; s = src[e];
            atomicAdd(&bcnt[d >> 7], 1);
        }
        myd[i] = d; mys[i] = s;
    }
    __syncthreads();
    int c = (t < NB) ? bcnt[t] : 0;
    part[t] = c; __syncthreads();
    for (int d = 1; d < 1024; d <<= 1) {
        int xk = (t >= d) ? part[t - d] : 0;
        __syncthreads();
        part[t] += xk;
        __syncthreads();
    }
    if (t < NB) {
        lstart[t] = part[t] - c;
        if (c) {
            gbase[t] = atomicAdd(&gcursor[t], (c + 15) & ~15);
            atomicAdd(&btot[t], c);
        }
    }
    __syncthreads();
    #pragma unroll
    for (int i = 0; i < 8; ++i) {
        int d = myd[i];
        if (d >= 0) {
            int b = d >> 7;
            int lp = atomicAdd(&bofs[b], 1);
            rec[lstart[b] + lp] = (u32)mys[i] | ((u32)(d & 127) << 17);
        }
    }
    __syncthreads();
    int wv = t >> 6, ln = t & 63;
    for (int b = wv; b < NB; b += 16) {
        int n = bcnt[b];
        if (n) {
            int np = (n + 15) & ~15;
            int gb = gbase[b], ls = lstart[b];
            for (int j = ln; j < np; j += 64)
                tmp[gb + j] = (j < n) ? rec[ls + j] : 0xFFFFFFFFu;
        }
    }
}

__global__ void k_bscan(const int* __restrict__ btot, int* __restrict__ bbase) {
    __shared__ int ls[1024];
    int t = threadIdx.x;
    int v = (t < NB) ? btot[t] : 0;
    ls[t] = v; __syncthreads();
    for (int d = 1; d < 1024; d <<= 1) {
        int x = (t >= d) ? ls[t - d] : 0;
        __syncthreads();
        ls[t] += x;
        __syncthreads();
    }
    if (t < NB) bbase[t] = ls[t] - v;   // exclusive
}

__global__ __launch_bounds__(256) void k_csrA(const u32* __restrict__ tmp,
                                              const int* __restrict__ gcursor,
                                              const int* __restrict__ bbase,
                                              int* __restrict__ rowp,
                                              int* __restrict__ cnt,
                                              float* __restrict__ dinv) {
    __shared__ int lcnt[128];
    __shared__ int lofs[128];
    int b = blockIdx.x, t = threadIdx.x;
    if (t < 128) lcnt[t] = 0;
    __syncthreads();
    int beg = b * BCAP, end = gcursor[b];
    for (int i = beg + t; i < end; i += 256) {
        u32 r = tmp[i];
        if (r != 0xFFFFFFFFu) atomicAdd(&lcnt[(r >> 17) & 127], 1);
    }
    __syncthreads();
    int c = (t < 128) ? lcnt[t] : 0;
    if (t < 128) lofs[t] = c;
    __syncthreads();
    for (int d = 1; d < 128; d <<= 1) {
        int x = 0;
        if (t < 128 && t >= d) x = lofs[t - d];
        __syncthreads();
        if (t < 128) lofs[t] += x;
        __syncthreads();
    }
    if (t < 128) {
        int n = (b << 7) + t;
        if (n < NN) {
            rowp[n] = bbase[b] + lofs[t] - c;
            cnt[n] = c;
            dinv[n] = rsqrtf(1.0f + (float)c);
        }
    }
}

// place records at CSR positions + weights; accumulate rowsum = sum(w) + dinv^2
__global__ __launch_bounds__(256) void k_csrB(const u32* __restrict__ tmp,
                                              const int* __restrict__ gcursor,
                                              const int* __restrict__ rowp,
                                              const float* __restrict__ dinv,
                                              int2* __restrict__ ew,
                                              float* __restrict__ rowsum) {
    __shared__ int lcur[128];
    __shared__ float ldin[128];
    __shared__ float lsum[128];
    int b = blockIdx.x, t = threadIdx.x;
    int n0 = b << 7;
    if (t < 128) {
        int n = n0 + t;
        lcur[t] = (n < NN) ? rowp[n] : 0;
        float dv = (n < NN) ? dinv[n] : 0.f;
        ldin[t] = dv;
        lsum[t] = dv * dv;
    }
    __syncthreads();
    int beg = b * BCAP;
    int end = gcursor[b];
    for (int i = beg + t; i < end; i += 256) {
        u32 r = tmp[i];
        if (r == 0xFFFFFFFFu) continue;   // padding sentinel
        int s = r & 0x1FFFF;
        int dl = (r >> 17) & 127;
        int pos = atomicAdd(&lcur[dl], 1);
        float w = dinv[s] * ldin[dl];
        ew[pos] = make_int2(s, __float_as_int(w));
        atomicAdd(&lsum[dl], w);
    }
    __syncthreads();
    if (t < 128) {
        int n = n0 + t;
        if (n < NN) rowsum[n] = lsum[t];
    }
}

// ---------------- SpMM layer 1: xp(bf16,64d) = A @ xb ----------------

__global__ __launch_bounds__(256) void k_spmm1(const u16* __restrict__ xb,
                                               const int* __restrict__ rowp,
                                               const int* __restrict__ cnt,
                                               const int2* __restrict__ ew,
                                               const float* __restrict__ dinv,
                                               u16* __restrict__ xp) {
    int wave = threadIdx.x >> 6;
    int lane = threadIdx.x & 63;
    int n = blockIdx.x * 4 + wave;          // grid exact: 25000 blocks
    int o = lane >> 3, li = lane & 7;       // o: edge slot 0..7, li: 16B chunk
    int f0 = li * 8;                        // 8 bf16 elements
    float dn = dinv[n];
    float a[8];
    {
        uint4 r = *(const uint4*)&xb[(size_t)n * DX + f0];
        float sc = (o == 0) ? dn * dn : 0.f;
        u32 wd[4] = {r.x, r.y, r.z, r.w};
        #pragma unroll
        for (int k = 0; k < 4; ++k) {
            a[k * 2 + 0] = sc * bf2f((u16)(wd[k] & 0xffff));
            a[k * 2 + 1] = sc * bf2f((u16)(wd[k] >> 16));
        }
    }
    int start = rowp[n], len = cnt[n];
    #pragma unroll 2
    for (int j = o; j < len; j += 8) {
        int2 e = ew[start + j];
        float wv = __int_as_float(e.y);
        uint4 r = *(const uint4*)&xb[(size_t)e.x * DX + f0];
        u32 wd[4] = {r.x, r.y, r.z, r.w};
        #pragma unroll
        for (int k = 0; k < 4; ++k) {
            a[k * 2 + 0] = fmaf(bf2f((u16)(wd[k] & 0xffff)), wv, a[k * 2 + 0]);
            a[k * 2 + 1] = fmaf(bf2f((u16)(wd[k] >> 16)),    wv, a[k * 2 + 1]);
        }
    }
    #pragma unroll
    for (int k = 0; k < 8; ++k) {
        a[k] += __shfl_xor(a[k], 8);
        a[k] += __shfl_xor(a[k], 16);
        a[k] += __shfl_xor(a[k], 32);
    }
    if (o == 0) {
        uint4 pk;
        u32 w0 = (u32)f2b(a[0]) | ((u32)f2b(a[1]) << 16);
        u32 w1 = (u32)f2b(a[2]) | ((u32)f2b(a[3]) << 16);
        u32 w2 = (u32)f2b(a[4]) | ((u32)f2b(a[5]) << 16);
        u32 w3 = (u32)f2b(a[6]) | ((u32)f2b(a[7]) << 16);
        pk = make_uint4(w0, w1, w2, w3);
        *(uint4*)&xp[(size_t)n * DX + f0] = pk;
    }
}

// ---------------- MFMA GEMM1: hbuf = relu(xp @ W1x + rowsum*cvec + b1) ----------------

__global__ __launch_bounds__(256) void k_mgemm1(const u16* __restrict__ xp,
                                                const u16* __restrict__ Bt1,
                                                const float* __restrict__ cvec,
                                                const float* __restrict__ b1,
                                                const float* __restrict__ rowsum,
                                                u16* __restrict__ outp) {
    __shared__ u16 As[64 * 64];
    __shared__ u16 Bs[128 * 64];    // reused as Cs (64 x 128)
    __shared__ float cvs[128], bs[128], rsum[64];
    int t = threadIdx.x;
    int n0 = blockIdx.x * 64;
    if (t < 128) { cvs[t] = cvec[t]; bs[t] = b1[t]; }
    if (t < 64) {
        int n = n0 + t;
        rsum[t] = (n < NN) ? rowsum[n] : 0.f;
    }

    #pragma unroll
    for (int l = 0; l < 4; ++l) {
        int idx = t + l * 256;
        int col = idx >> 3, kg = idx & 7;
        uint4 v = *(const uint4*)&Bt1[idx * 8];
        u32 byte = (u32)(col * 128 + kg * 16) ^ ((col & 7) << 4);
        *(uint4*)((char*)Bs + byte) = v;
    }
    #pragma unroll
    for (int l = 0; l < 2; ++l) {
        int idx = t + l * 256;
        int r = idx >> 3, kg = idx & 7;
        int n = n0 + r; if (n > NN - 1) n = NN - 1;
        uint4 v = *(const uint4*)&xp[(size_t)n * DX + kg * 8];
        u32 byte = (u32)(r * 128 + kg * 16) ^ ((r & 7) << 4);
        *(uint4*)((char*)As + byte) = v;
    }
    __syncthreads();

    int w = t >> 6, lane = t & 63;
    int rl = lane & 15, kq = lane >> 4;
    int rbase = w * 16 + rl;
    float4v acc[8];
    #pragma unroll
    for (int nt = 0; nt < 8; ++nt) acc[nt] = (float4v){0.f, 0.f, 0.f, 0.f};

    #pragma unroll
    for (int kk = 0; kk < 2; ++kk) {
        u32 ab = (u32)(rbase * 128 + kk * 64 + kq * 16) ^ ((rbase & 7) << 4);
        short8v af = *(const short8v*)((const char*)As + ab);
        #pragma unroll
        for (int nt = 0; nt < 8; ++nt) {
            int col = nt * 16 + rl;
            u32 bb = (u32)(col * 128 + kk * 64 + kq * 16) ^ ((col & 7) << 4);
            short8v bf = *(const short8v*)((const char*)Bs + bb);
            acc[nt] = __builtin_amdgcn_mfma_f32_16x16x32_bf16(af, bf, acc[nt], 0, 0, 0);
        }
    }
    __syncthreads();
    #pragma unroll
    for (int nt = 0; nt < 8; ++nt) {
        int col = nt * 16 + rl;
        #pragma unroll
        for (int j = 0; j < 4; ++j) {
            int row = w * 16 + kq * 4 + j;
            float o = acc[nt][j] + rsum[row] * cvs[col] + bs[col];
            u16 v = f2b(fmaxf(o, 0.f));
            u32 byte = (u32)(row * 256 + col * 2) ^ ((row & 7) << 4);
            *(u16*)((char*)Bs + byte) = v;
        }
    }
    __syncthreads();
    #pragma unroll
    for (int l = 0; l < 4; ++l) {
        int idx = t + l * 256;
        int r = idx >> 4, kg = idx & 15;
        u32 byte = (u32)(r * 256 + kg * 16) ^ ((r & 7) << 4);
        uint4 v = *(const uint4*)((const char*)Bs + byte);
        int n = n0 + r;
        if (n < NN) *(uint4*)&outp[(size_t)n * HH + kg * 8] = v;
    }
}

// ---------------- MFMA GEMM2: h8(fp8) = bn1(hbuf) @ W2 ----------------

__global__ __launch_bounds__(256) void k_mgemm2(const u16* __restrict__ hin,
                                                const u16* __restrict__ Bt2,
                                                const float* __restrict__ stats,
                                                const float* __restrict__ g,
                                                const float* __restrict__ be,
                                                u8* __restrict__ outp8) {
    __shared__ u16 As[64 * 128];    // staging; reused as fp8 Cs (64 x 128 B)
    __shared__ u16 Bs[128 * 128];
    __shared__ float asc[128], csc[128];
    int t = threadIdx.x;
    int n0 = blockIdx.x * 64;
    if (t < 128) {
        float mu  = stats[t] * (1.0f / NN);
        float var = stats[128 + t] * (1.0f / NN) - mu * mu;
        float rs  = rsqrtf(var + EPSV);
        float a   = g[t] * rs;
        asc[t] = a;
        csc[t] = be[t] - mu * a;
    }
    #pragma unroll
    for (int l = 0; l < 8; ++l) {
        int idx = t + l * 256;
        int col = idx >> 4, kg = idx & 15;
        uint4 v = *(const uint4*)&Bt2[idx * 8];
        u32 byte = (u32)(col * 256 + kg * 16) ^ ((col & 7) << 4);
        *(uint4*)((char*)Bs + byte) = v;
    }
    __syncthreads();
    #pragma unroll
    for (int l = 0; l < 4; ++l) {
        int idx = t + l * 256;
        int r = idx >> 4, kg = idx & 15;
        int n = n0 + r; if (n > NN - 1) n = NN - 1;
        uint4 v = *(const uint4*)&hin[(size_t)n * HH + kg * 8];
        u32 wds[4] = {v.x, v.y, v.z, v.w};
        u32 pk[2][2];
        #pragma unroll
        for (int q = 0; q < 4; ++q) {
            int k = kg * 8 + q * 2;
            float x0 = bf2f((u16)(wds[q] & 0xffff));
            float x1 = bf2f((u16)(wds[q] >> 16));
            u16 o0 = f2b(fmaxf(fmaf(x0, asc[k],     csc[k]),     0.f));
            u16 o1 = f2b(fmaxf(fmaf(x1, asc[k + 1], csc[k + 1]), 0.f));
            pk[q >> 1][q & 1] = (u32)o0 | ((u32)o1 << 16);
        }
        uint4 ov = make_uint4(pk[0][0], pk[0][1], pk[1][0], pk[1][1]);
        u32 byte = (u32)(r * 256 + kg * 16) ^ ((r & 7) << 4);
        *(uint4*)((char*)As + byte) = ov;
    }
    __syncthreads();

    int w = t >> 6, lane = t & 63;
    int rl = lane & 15, kq = lane >> 4;
    int rbase = w * 16 + rl;
    float4v acc[8];
    #pragma unroll
    for (int nt = 0; nt < 8; ++nt) acc[nt] = (float4v){0.f, 0.f, 0.f, 0.f};

    #pragma unroll
    for (int kk = 0; kk < 4; ++kk) {
        u32 ab = (u32)(rbase * 256 + kk * 64 + kq * 16) ^ ((rbase & 7) << 4);
        short8v af = *(const short8v*)((const char*)As + ab);
        #pragma unroll
        for (int nt = 0; nt < 8; ++nt) {
            int col = nt * 16 + rl;
            u32 bb = (u32)(col * 256 + kk * 64 + kq * 16) ^ ((col & 7) << 4);
            short8v bf = *(const short8v*)((const char*)Bs + bb);
            acc[nt] = __builtin_amdgcn_mfma_f32_16x16x32_bf16(af, bf, acc[nt], 0, 0, 0);
        }
    }
    __syncthreads();
    // epilogue: acc -> fp8 Cs (64 rows x 128 B, chunk-swizzled)
    u8* Cs8 = (u8*)As;
    #pragma unroll
    for (int nt = 0; nt < 8; ++nt) {
        int col = nt * 16 + rl;
        #pragma unroll
        for (int j = 0; j < 4; ++j) {
            int row = w * 16 + kq * 4 + j;
            u32 pk8 = __builtin_amdgcn_cvt_pk_fp8_f32(acc[nt][j], acc[nt][j], 0, false);
            u32 byte = (u32)(row * 128 + col) ^ ((row & 7) << 4);
            Cs8[byte] = (u8)(pk8 & 0xff);
        }
    }
    __syncthreads();
    #pragma unroll
    for (int l = 0; l < 2; ++l) {
        int idx = t + l * 256;
        int r = idx >> 3, kg = idx & 7;
        u32 byte = (u32)(r * 128 + kg * 16) ^ ((r & 7) << 4);
        uint4 v = *(const uint4*)(Cs8 + byte);
        int n = n0 + r;
        if (n < NN) *(uint4*)&outp8[(size_t)n * HH + kg * 16] = v;
    }
}

// ---------------- SpMM layer 2 (fp8 gather): hout = relu(A @ h8 + b2) ----------------
// QUARTER-wave (16 lanes x 8B = full 128B fp8 row) per edge; 4 edge slots,
// unroll 4 (matched to ~4 mean trip count); 8 regs, 2-hop reduce.

__global__ __launch_bounds__(256) void k_spmm2(const u8* __restrict__ h8,
                                               const int* __restrict__ rowp,
                                               const int* __restrict__ cnt,
                                               const int2* __restrict__ ew,
                                               const float* __restrict__ dinv,
                                               const float* __restrict__ b,
                                               u16* __restrict__ hout) {
    int wave = threadIdx.x >> 6;
    int lane = threadIdx.x & 63;
    int n = blockIdx.x * 4 + wave;          // grid exact: 25000 blocks
    int q = lane >> 4, li = lane & 15;      // q: edge slot 0..3, li: 8B chunk
    int f0 = li * 8;                        // 8 fp8 features per lane
    float dn = dinv[n];
    float a[8];
    {
        uint2 r = *(const uint2*)&h8[(size_t)n * HH + f0];
        float sc = (q == 0) ? dn * dn : 0.f;
        u32 wd[2] = {r.x, r.y};
        #pragma unroll
        for (int k = 0; k < 2; ++k) {
            float2v lo = __builtin_amdgcn_cvt_pk_f32_fp8(wd[k], false);
            float2v hi = __builtin_amdgcn_cvt_pk_f32_fp8(wd[k], true);
            a[k * 4 + 0] = sc * lo[0];
            a[k * 4 + 1] = sc * lo[1];
            a[k * 4 + 2] = sc * hi[0];
            a[k * 4 + 3] = sc * hi[1];
        }
    }
    int start = rowp[n], len = cnt[n];
    #pragma unroll 4
    for (int j = q; j < len; j += 4) {
        int2 e = ew[start + j];
        float wv = __int_as_float(e.y);
        uint2 r = *(const uint2*)&h8[(size_t)e.x * HH + f0];
        u32 wd[2] = {r.x, r.y};
        #pragma unroll
        for (int k = 0; k < 2; ++k) {
            float2v lo = __builtin_amdgcn_cvt_pk_f32_fp8(wd[k], false);
            float2v hi = __builtin_amdgcn_cvt_pk_f32_fp8(wd[k], true);
            a[k * 4 + 0] = fmaf(lo[0], wv, a[k * 4 + 0]);
            a[k * 4 + 1] = fmaf(lo[1], wv, a[k * 4 + 1]);
            a[k * 4 + 2] = fmaf(hi[0], wv, a[k * 4 + 2]);
            a[k * 4 + 3] = fmaf(hi[1], wv, a[k * 4 + 3]);
        }
    }
    #pragma unroll
    for (int k = 0; k < 8; ++k) {
        a[k] += __shfl_xor(a[k], 16);
        a[k] += __shfl_xor(a[k], 32);
    }
    if (q == 0) {
        float4 b0 = *(const float4*)&b[f0];
        float4 b1 = *(const float4*)&b[f0 + 4];
        float bb[8] = {b0.x, b0.y, b0.z, b0.w, b1.x, b1.y, b1.z, b1.w};
        u32 ow[4];
        #pragma unroll
        for (int k = 0; k < 4; ++k) {
            float v0 = fmaxf(a[k * 2 + 0] + bb[k * 2 + 0], 0.f);
            float v1 = fmaxf(a[k * 2 + 1] + bb[k * 2 + 1], 0.f);
            ow[k] = (u32)f2b(v0) | ((u32)f2b(v1) << 16);
        }
        *(uint4*)&hout[(size_t)n * HH + f0] = make_uint4(ow[0], ow[1], ow[2], ow[3]);
    }
}

// ---------------- BN stats (streaming, separate) ----------------

__global__ __launch_bounds__(256) void k_stats(const u16* __restrict__ h,
                                               float* __restrict__ sums) {
    __shared__ float4 ls[4][64];
    int t = threadIdx.x;
    int lane = t & 63, wave = t >> 6;
    int f0 = lane * 2;
    float s0 = 0.f, s1 = 0.f, q0 = 0.f, q1 = 0.f;
    for (int row = blockIdx.x * 4 + wave; row < NN; row += gridDim.x * 4) {
        u32 v = *(const u32*)&h[(size_t)row * HH + f0];
        float a = bf2f((u16)(v & 0xffff));
        float c = bf2f((u16)(v >> 16));
        s0 += a; q0 += a * a;
        s1 += c; q1 += c * c;
    }
    ls[wave][lane] = make_float4(s0, s1, q0, q1);
    __syncthreads();
    if (wave == 0) {
        float4 r0 = ls[0][lane], r1 = ls[1][lane], r2 = ls[2][lane], r3 = ls[3][lane];
        atomicAdd(&sums[f0 + 0], r0.x + r1.x + r2.x + r3.x);
        atomicAdd(&sums[f0 + 1], r0.y + r1.y + r2.y + r3.y);
        atomicAdd(&sums[128 + f0 + 0], r0.z + r1.z + r2.z + r3.z);
        atomicAdd(&sums[128 + f0 + 1], r0.w + r1.w + r2.w + r3.w);
    }
}

// ---------------- output head ----------------

__global__ __launch_bounds__(256) void k_out(const u16* __restrict__ h,
                                             const float* __restrict__ stats,
                                             const float* __restrict__ g,
                                             const float* __restrict__ be,
                                             const float* __restrict__ Wout,
                                             const float* __restrict__ bout,
                                             float* __restrict__ out) {
    __shared__ float hs[32][132];
    __shared__ float Wl[128][8];
    __shared__ float asc[128], csc[128];
    int t = threadIdx.x;
    if (t < 128) {
        float mu  = stats[256 + t] * (1.0f / NN);
        float var = stats[384 + t] * (1.0f / NN) - mu * mu;
        float rs  = rsqrtf(var + EPSV);
        float a   = g[t] * rs;
        asc[t] = a;
        csc[t] = be[t] - mu * a;
    }
    #pragma unroll
    for (int l = 0; l < 4; ++l) {
        int idx = t + l * 256;
        Wl[idx >> 3][idx & 7] = Wout[idx];
    }
    __syncthreads();

    int n0 = blockIdx.x * 32;
    #pragma unroll
    for (int l = 0; l < 2; ++l) {
        int idx = t + l * 256;
        int r = idx >> 4;
        int kg = idx & 15;
        uint4 v = *(const uint4*)&h[(size_t)(n0 + r) * HH + kg * 8];
        u32 w[4] = {v.x, v.y, v.z, v.w};
        int kk = kg * 8;
        #pragma unroll
        for (int qq = 0; qq < 4; ++qq) {
            float x0 = bf2f((u16)(w[qq] & 0xffff));
            float x1 = bf2f((u16)(w[qq] >> 16));
            hs[r][kk + qq * 2 + 0] = fmaxf(fmaf(x0, asc[kk + qq * 2 + 0], csc[kk + qq * 2 + 0]), 0.f);
            hs[r][kk + qq * 2 + 1] = fmaxf(fmaf(x1, asc[kk + qq * 2 + 1], csc[kk + qq * 2 + 1]), 0.f);
        }
    }
    __syncthreads();

    int c = t & 7, rl = t >> 3;
    float acc = 0.f;
    #pragma unroll 8
    for (int k = 0; k < 128; ++k) acc = fmaf(hs[rl][k], Wl[k][c], acc);
    out[(size_t)(n0 + rl) * CC + c] = acc + bout[c];
}

// ---------------- launch ----------------

extern "C" void kernel_launch(void* const* d_in, const int* in_sizes, int n_in,
                              void* d_out, int out_size, void* d_ws, size_t ws_size,
                              hipStream_t stream) {
    const float* x    = (const float*)d_in[0];
    const int*   src  = (const int*)d_in[1];
    const int*   dst  = (const int*)d_in[2];
    const float* sctx = (const float*)d_in[3];
    const float* W1   = (const float*)d_in[4];
    const float* b1   = (const float*)d_in[5];
    const float* g1   = (const float*)d_in[6];
    const float* be1  = (const float*)d_in[7];
    const float* W2   = (const float*)d_in[8];
    const float* b2   = (const float*)d_in[9];
    const float* g2   = (const float*)d_in[10];
    const float* be2  = (const float*)d_in[11];
    const float* Wout = (const float*)d_in[12];
    const float* bout = (const float*)d_in[13];
    float* out = (float*)d_out;

    char* p = (char*)d_ws;
    auto carve = [&](size_t bytes) -> char* {
        char* r = p;
        p += (bytes + 255) & ~(size_t)255;
        return r;
    };
    u16*   hbuf    = (u16*)carve((size_t)NN * HH * 2);
    u8*    h8      = (u8*)carve((size_t)NN * HH);
    u16*   xb      = (u16*)carve((size_t)NN * DX * 2);
    u16*   xp      = (u16*)carve((size_t)NN * DX * 2);
    int2*  ew      = (int2*)carve((size_t)EE * 8 + 16);
    u32*   tmp     = (u32*)carve((size_t)NB * BCAP * 4 + 16);
    int*   cnt     = (int*)carve((size_t)NN * 4);
    int*   rowp    = (int*)carve((size_t)NN * 4);
    int*   gcursor = (int*)carve((size_t)NB * 4);
    int*   btot    = (int*)carve((size_t)NB * 4);
    int*   bbase   = (int*)carve((size_t)NB * 4);
    float* dinv    = (float*)carve((size_t)NN * 4);
    float* rowsum  = (float*)carve((size_t)NN * 4);
    float* cvec    = (float*)carve(128 * 4);
    float* stats   = (float*)carve(512 * 4);
    u16*   Bt1     = (u16*)carve(128 * 64 * 2);
    u16*   Bt2     = (u16*)carve(128 * 128 * 2);

    k_setup<<<(NN * (DX / 4) + 255) / 256, 256, 0, stream>>>(
        sctx, W1, W2, x, stats, btot, gcursor, cvec, Bt1, Bt2, xb);
    k_bin<<<NBLK_BIN, 1024, 0, stream>>>(src, dst, btot, gcursor, tmp);
    k_bscan<<<1, 1024, 0, stream>>>(btot, bbase);
    k_csrA<<<NB, 256, 0, stream>>>(tmp, gcursor, bbase, rowp, cnt, dinv);
    k_csrB<<<NB, 256, 0, stream>>>(tmp, gcursor, rowp, dinv, ew, rowsum);

    k_spmm1<<<NN / 4, 256, 0, stream>>>(xb, rowp, cnt, ew, dinv, xp);
    k_mgemm1<<<(NN + 63) / 64, 256, 0, stream>>>(xp, Bt1, cvec, b1, rowsum, hbuf);
    k_stats<<<512, 256, 0, stream>>>(hbuf, stats);
    k_mgemm2<<<(NN + 63) / 64, 256, 0, stream>>>(hbuf, Bt2, stats, g1, be1, h8);
    k_spmm2<<<NN / 4, 256, 0, stream>>>(h8, rowp, cnt, ew, dinv, b2, hbuf);
    k_stats<<<512, 256, 0, stream>>>(hbuf, stats + 256);
    k_out<<<NN / 32, 256, 0, stream>>>(hbuf, stats, g2, be2, Wout, bout, out);
}